// Round 1
// baseline (117.969 us; speedup 1.0000x reference)
//
#include <hip/hip_runtime.h>
#include <math.h>

#define NTH   256
#define T_PER 32
#define HALO  256
#define CHUNK (NTH * T_PER)          // 8192 outputs per block
#define NDATA (CHUNK + 2 * HALO)     // 8704 staged rhs values
#define NPAD  (NDATA + NDATA / 32)   // padded LDS floats (8976)

// padded LDS index: +1 float per 32 to break stride-32 bank conflicts
__device__ __forceinline__ int pidx(int k) { return k + (k >> 5); }

__global__ void __launch_bounds__(NTH, 4)
diffusion_thomas(const float* __restrict__ C, const float* __restrict__ dtp,
                 const float* __restrict__ csp, const float* __restrict__ cbp,
                 float* __restrict__ out, int n)
{
    __shared__ float s[NPAD];
    const int tid = threadIdx.x;
    const int bs  = blockIdx.x * CHUNK;   // first output index of this block

    const float dt = dtp[0], Cs = csp[0], Cb = cbp[0];
    // constant coefficients (double for setup only)
    const double rd    = 1e-5 * (double)dt / (1e-4 * 1e-4);
    const double sq    = sqrt(1.0 + 4.0 * rd);
    const double betad = 2.0 * rd / ((1.0 + 2.0 * rd) + sq);   // decay root in (0,1)
    const double g0d   = 1.0 / ((1.0 + 2.0 * rd) - 2.0 * rd * betad);
    const float  r     = (float)rd;
    const float  beta  = (float)betad;
    const float  G0    = (float)g0d;
    const float  lbeta = (float)log(betad);

    // ---- stage modified RHS window [bs-HALO, bs+CHUNK+HALO) into padded LDS ----
    // rhsv[0]=rhsv[n-1]=0 (Dirichlet rows removed), rhsv[1]+=r*Cs, rhsv[n-2]+=r*Cb,
    // out-of-domain = 0 (truncation).
    for (int k = tid; k < NDATA; k += NTH) {
        int g = bs - HALO + k;
        float v = 0.0f;
        if (g >= 1 && g <= n - 2) {
            v = C[g];
            if (g == 1)     v = fmaf(r, Cs, v);
            if (g == n - 2) v = fmaf(r, Cb, v);
        }
        s[pidx(k)] = v;
    }
    __syncthreads();

    const int l0   = tid * T_PER;      // local coord of first output (32-aligned)
    const int bL   = pidx(l0);         // window start   (LDS, padded)
    const int bM   = pidx(l0 + HALO);  // output region  (LDS, padded)
    const int bR   = pidx(l0 + HALO + T_PER); // right halo start

    // ---- forward attenuated scan: F_i = sum_{j<=i} beta^(i-j) rhs_j (window) ----
    float f = 0.0f;
#pragma unroll 32
    for (int k = 0; k < HALO; ++k)
        f = fmaf(beta, f, s[bL + k + (k >> 5)]);
    float F[T_PER];
#pragma unroll
    for (int k = 0; k < T_PER; ++k) {
        f = fmaf(beta, f, s[bM + k + (k >> 5)]);
        F[k] = f;
    }

    // ---- backward attenuated scan, fused with combine: x = G0*(F+B-rhs) ----
    float b = 0.0f;
#pragma unroll 32
    for (int k = HALO - 1; k >= 0; --k)
        b = fmaf(beta, b, s[bR + k + (k >> 5)]);
#pragma unroll
    for (int k = T_PER - 1; k >= 0; --k) {
        float rv = s[bM + k + (k >> 5)];
        b = fmaf(beta, b, rv);
        F[k] = G0 * (F[k] + b - rv);    // F[] now holds x
    }

    // ---- left boundary: image correction + Dirichlet override ----
    if (blockIdx.x == 0) {
        if (l0 < 256) {                 // beta^256*P_L ~ 4e-11: only threads 0..7
            float acc = 0.0f;
            for (int j = 512; j >= 1; --j)
                acc = fmaf(beta, acc, s[pidx(HALO + j)]);
            const float PL = G0 * beta * acc;
            float bp = __expf(lbeta * (float)l0);   // beta^l0
#pragma unroll
            for (int k = 0; k < T_PER; ++k) {
                F[k] = fmaf(-bp, PL, F[k]);
                bp *= beta;
            }
        }
        if (tid == 0) F[0] = Cs;        // x_0 = C_surf exactly
    }

    // ---- right boundary: mirror image correction + Dirichlet override ----
    if (blockIdx.x == gridDim.x - 1) {
        const int i0g = bs + l0;
        if (i0g + T_PER - 1 >= n - 256) {
            float acc = 0.0f;
            const int jlo = n - 1 - 512;
            for (int j = jlo; j <= n - 2; ++j)
                acc = fmaf(beta, acc, s[pidx(j - bs + HALO)]);
            const float PR = G0 * beta * acc;
#pragma unroll
            for (int k = 0; k < T_PER; ++k) {
                int i = i0g + k;
                if (i <= n - 2) {
                    float e = __expf(lbeta * (float)(n - 1 - i)); // beta^(n-1-i)
                    F[k] = fmaf(-e, PR, F[k]);
                }
            }
        }
#pragma unroll
        for (int k = 0; k < T_PER; ++k)
            if (i0g + k == n - 1) F[k] = Cb;   // x_{n-1} = C_bulk exactly
    }

    // ---- stage x through LDS for coalesced stores ----
    __syncthreads();                   // everyone done reading data buffer
#pragma unroll
    for (int k = 0; k < T_PER; ++k)
        s[bL + k + (k >> 5)] = F[k];   // x at padded position pidx(l0+k)
    __syncthreads();
    for (int k = tid; k < CHUNK; k += NTH) {
        int g = bs + k;
        if (g < n) out[g] = s[pidx(k)];
    }
}

extern "C" void kernel_launch(void* const* d_in, const int* in_sizes, int n_in,
                              void* d_out, int out_size, void* d_ws, size_t ws_size,
                              hipStream_t stream) {
    const float* C  = (const float*)d_in[0];
    const float* dt = (const float*)d_in[1];
    const float* cs = (const float*)d_in[2];
    const float* cb = (const float*)d_in[3];
    float* out = (float*)d_out;
    const int n  = in_sizes[0];
    const int nb = (n + CHUNK - 1) / CHUNK;   // 512 for n = 4,194,304
    diffusion_thomas<<<nb, NTH, 0, stream>>>(C, dt, cs, cb, out, n);
}

// Round 2
// 78.378 us; speedup vs baseline: 1.5051x; 1.5051x over previous
//
#include <hip/hip_runtime.h>
#include <math.h>

#define NTH   256
#define T_PER 10
#define HALO  256
#define NDATA (NTH * T_PER)          // 2560 staged rhs values per block
#define CHUNK (NDATA - 2 * HALO)     // 2048 outputs per block

// Blocked parallel attenuated scan solver for the constant-coefficient
// Thomas system: x = G0 * sum_j beta^|i-j| d_j, with image-charge
// corrections at the two Dirichlet boundaries.
__global__ void __launch_bounds__(NTH, 4)
diffusion_thomas(const float* __restrict__ C, const float* __restrict__ dtp,
                 const float* __restrict__ csp, const float* __restrict__ cbp,
                 float* __restrict__ out, int n)
{
    __shared__ __align__(16) float s[NDATA];
    __shared__ float waggF[4], waggB[4], sPL, sPR;

    const int tid  = threadIdx.x;
    const int lane = tid & 63;
    const int w    = tid >> 6;
    const int bs   = (int)blockIdx.x * CHUNK;   // first output index
    const int wbase = bs - HALO;                // global index of s[0]
    const bool isB0   = (blockIdx.x == 0);
    const bool isLast = (blockIdx.x == gridDim.x - 1);

    const float dt = dtp[0], Cs = csp[0], Cb = cbp[0];
    // exact coefficient setup in double (once per thread, cheap)
    const double rd    = 1e-5 * (double)dt / (1e-4 * 1e-4);
    const double sq    = sqrt(1.0 + 4.0 * rd);
    const double betad = 2.0 * rd / ((1.0 + 2.0 * rd) + sq);   // decay root
    const double g0d   = 1.0 / ((1.0 + 2.0 * rd) - 2.0 * rd * betad);
    // powers of beta by squaring: A_k = beta^(T_PER * k)
    const double b2 = betad*betad, b4 = b2*b2, b8 = b4*b4, b10 = b8*b2;
    const double a2 = b10*b10, a4 = a2*a2, a8 = a4*a4, a16 = a8*a8, a32 = a16*a16;
    const double b640 = a32*a32;
    const float beta = (float)betad, G0 = (float)g0d, r = (float)rd;
    const float lbeta = (float)log(betad);
    const float A1=(float)b10, A2=(float)a2, A4=(float)a4,
                A8=(float)a8, A16=(float)a16, A32=(float)a32, B640=(float)b640;

    // ---- stage modified RHS window into LDS (float4, coalesced) ----
    // d[0]=d[n-1]=0 (Dirichlet rows removed), d[1]+=r*Cs, d[n-2]+=r*Cb,
    // out-of-domain = 0.
    for (int k4 = tid; k4 < NDATA / 4; k4 += NTH) {
        int g0 = wbase + 4 * k4;
        float4 v;
        if (g0 >= 2 && g0 + 3 <= n - 3) {
            v = *reinterpret_cast<const float4*>(C + g0);
        } else {
            float t0[4];
#pragma unroll
            for (int e = 0; e < 4; ++e) {
                int g = g0 + e; float x = 0.0f;
                if (g >= 1 && g <= n - 2) {
                    x = C[g];
                    if (g == 1)     x = fmaf(r, Cs, x);
                    if (g == n - 2) x = fmaf(r, Cb, x);
                }
                t0[e] = x;
            }
            v = make_float4(t0[0], t0[1], t0[2], t0[3]);
        }
        *reinterpret_cast<float4*>(&s[4 * k4]) = v;
    }
    __syncthreads();

    // ---- pass 1: per-thread segment aggregates (T=10, both directions) ----
    const int l0 = tid * T_PER;
    float d[T_PER];
#pragma unroll
    for (int j = 0; j < T_PER; ++j) d[j] = s[l0 + j];
    float Sf = 0.0f, Sb = 0.0f;
#pragma unroll
    for (int j = 0; j < T_PER; ++j) {          // two independent chains (ILP)
        Sf = fmaf(beta, Sf, d[j]);
        Sb = fmaf(beta, Sb, d[T_PER - 1 - j]);
    }

    // ---- wave-level attenuated Hillis-Steele scans (6 shfl steps) ----
    float c = Sf, cbk = Sb, u;
    u = __shfl_up(c, 1);    if (lane >= 1)  c = fmaf(A1,  u, c);
    u = __shfl_up(c, 2);    if (lane >= 2)  c = fmaf(A2,  u, c);
    u = __shfl_up(c, 4);    if (lane >= 4)  c = fmaf(A4,  u, c);
    u = __shfl_up(c, 8);    if (lane >= 8)  c = fmaf(A8,  u, c);
    u = __shfl_up(c, 16);   if (lane >= 16) c = fmaf(A16, u, c);
    u = __shfl_up(c, 32);   if (lane >= 32) c = fmaf(A32, u, c);
    u = __shfl_down(cbk, 1);  if (lane <= 62) cbk = fmaf(A1,  u, cbk);
    u = __shfl_down(cbk, 2);  if (lane <= 61) cbk = fmaf(A2,  u, cbk);
    u = __shfl_down(cbk, 4);  if (lane <= 59) cbk = fmaf(A4,  u, cbk);
    u = __shfl_down(cbk, 8);  if (lane <= 55) cbk = fmaf(A8,  u, cbk);
    u = __shfl_down(cbk, 16); if (lane <= 47) cbk = fmaf(A16, u, cbk);
    u = __shfl_down(cbk, 32); if (lane <= 31) cbk = fmaf(A32, u, cbk);

    if (lane == 63) waggF[w] = c;      // wave-inclusive fwd aggregate
    if (lane == 0)  waggB[w] = cbk;    // wave-inclusive bwd aggregate
    __syncthreads();

    // cross-wave carries (640 elements/wave; B640 ~ 1.6e-28 but exact form kept)
    float Cw = 0.0f;
    for (int wp = 0; wp < w; ++wp)  Cw  = fmaf(B640, Cw,  waggF[wp]);
    float CwB = 0.0f;
    for (int wp = 3; wp > w; --wp)  CwB = fmaf(B640, CwB, waggB[wp]);

    float cup = __shfl_up(c, 1);
    float carryF = (lane == 0) ? Cw
                 : fmaf(__expf(lbeta * (float)(T_PER * lane)), Cw, cup);
    float cdn = __shfl_down(cbk, 1);
    float carryB = (lane == 63) ? CwB
                 : fmaf(__expf(lbeta * (float)(T_PER * (63 - lane))), CwB, cdn);

    // ---- pass 2: forward fixup, F[j] = f(l0+j) ----
    float F[T_PER];
    float f = carryF;
#pragma unroll
    for (int j = 0; j < T_PER; ++j) {
        f = fmaf(beta, f, d[j]);
        F[j] = f;
        if (isLast && (wbase + l0 + j) == n - 2) sPR = G0 * beta * f;  // x_free(n-1)
    }

    // ---- pass 3: backward fixup + combine x = G0*(f + b - d) ----
    float b = carryB;
#pragma unroll
    for (int j = T_PER - 1; j >= 0; --j) {
        b = fmaf(beta, b, d[j]);
        if (isB0 && (l0 + j) == HALO) sPL = G0 * b;                    // x_free(0)
        F[j] = G0 * (F[j] + b - d[j]);     // F[] now holds x
    }

    __syncthreads();   // sPL/sPR visible; all pass-1 LDS reads long done

    // ---- boundary image corrections + Dirichlet overrides ----
    if (isB0) {
        float PL = sPL;
#pragma unroll
        for (int j = 0; j < T_PER; ++j) {
            int i = l0 + j - HALO;
            if (i >= 1 && i < 512)
                F[j] = fmaf(-__expf(lbeta * (float)i), PL, F[j]);
            if (i == 0) F[j] = Cs;
        }
    }
    if (isLast) {
        float PR = sPR;
#pragma unroll
        for (int j = 0; j < T_PER; ++j) {
            int g = wbase + l0 + j;
            if (g >= n - 512 && g <= n - 2)
                F[j] = fmaf(-__expf(lbeta * (float)(n - 1 - g)), PR, F[j]);
            if (g == n - 1) F[j] = Cb;
        }
    }

    // ---- x back through LDS for coalesced float4 stores ----
#pragma unroll
    for (int j = 0; j < T_PER; ++j) s[l0 + j] = F[j];   // own segment only
    __syncthreads();
    for (int k4 = tid; k4 < CHUNK / 4; k4 += NTH) {
        int g0 = bs + 4 * k4;
        float4 v = *reinterpret_cast<const float4*>(&s[HALO + 4 * k4]);
        if (g0 + 3 < n) {
            *reinterpret_cast<float4*>(out + g0) = v;
        } else {
            if (g0     < n) out[g0]     = v.x;
            if (g0 + 1 < n) out[g0 + 1] = v.y;
            if (g0 + 2 < n) out[g0 + 2] = v.z;
            if (g0 + 3 < n) out[g0 + 3] = v.w;
        }
    }
}

extern "C" void kernel_launch(void* const* d_in, const int* in_sizes, int n_in,
                              void* d_out, int out_size, void* d_ws, size_t ws_size,
                              hipStream_t stream) {
    const float* C  = (const float*)d_in[0];
    const float* dt = (const float*)d_in[1];
    const float* cs = (const float*)d_in[2];
    const float* cb = (const float*)d_in[3];
    float* out = (float*)d_out;
    const int n  = in_sizes[0];
    const int nb = (n + CHUNK - 1) / CHUNK;   // 2048 blocks for n = 4,194,304
    diffusion_thomas<<<nb, NTH, 0, stream>>>(C, dt, cs, cb, out, n);
}